// Round 9
// baseline (512.244 us; speedup 1.0000x reference)
//
#include <hip/hip_runtime.h>
#include <stdint.h>

// GraphSAGE on MI355X — round 8: fire-and-forget staging.
// Theory: rounds 2-7 all capped at ~4.1 TB/s effective read BW because
// register-staged loads limit per-CU in-flight bytes (Little's law needs
// ~9.5 KB/CU; VGPR-windowed loads give ~5-6 KB). Fix: global_load_lds +
// counted s_waitcnt vmcnt(N) (T3/T4) — payload bypasses VGPRs, loads stay
// outstanding across barriers.
//
//  K1 (sage_k1): layer 1, BM=80 rows/block (1250 job1 + 125 job0 blocks, exact).
//    K=512 in 32 slices of 16 cols. Per slice s:
//      consume raw[s&1] (mean10 / convert) -> lAp half   [LDS only]
//      s odd: barrier; MFMA K=32 (A from lAp, B from lW[p&1])  [LDS only]
//      barrier; issue gl_lds stage(s+2): raw rows + (odd) W1t k-slice
//      s_waitcnt vmcnt(I(s+2))  -- counted, never drains pipeline
//      barrier
//    LDS: raw dbuf 2x52K + lW dbuf 2x16K + lAp 6.4K = 142.25 KB (dynamic).
//  K2 (sage_l2): layer 2, round-5's proven 16-row tile kernel.

typedef unsigned short u16;
typedef __attribute__((ext_vector_type(4))) float f32x4;
typedef __attribute__((ext_vector_type(8))) short s16x8;
typedef __attribute__((ext_vector_type(4))) unsigned short u16x4;

__device__ inline u16 f2bf(float x) {
    union { float f; uint32_t u; } v; v.f = x;
    uint32_t b = v.u;
    b += 0x7FFFu + ((b >> 16) & 1u);   // round-to-nearest-even
    return (u16)(b >> 16);
}
__device__ inline float bf2f(u16 u) {
    union { uint32_t u; float f; } v; v.u = ((uint32_t)u) << 16;
    return v.f;
}

// Transposed bf16 weight build: dst[n][koff+k] = f2bf(src[k][n]), 64x64 tiles.
__global__ __launch_bounds__(256) void conv_w2t(const float* __restrict__ w1s,
                                                const float* __restrict__ w1n,
                                                const float* __restrict__ w2s,
                                                const float* __restrict__ w2n,
                                                u16* __restrict__ W1t,
                                                u16* __restrict__ W2t) {
    __shared__ u16 t[64][66];
    const int b = blockIdx.x;
    const int mat = b >> 4;
    const int tk = ((b >> 2) & 3) * 64;
    const int tn = (b & 3) * 64;
    const float* src = (mat == 0) ? w1s : (mat == 1) ? w1n : (mat == 2) ? w2s : w2n;
    u16* dst = (mat < 2) ? W1t : W2t;
    const int koff = (mat & 1) * 256;
    const int tid = threadIdx.x;
    const int li = tid >> 6, ln = tid & 63;
    #pragma unroll
    for (int p = 0; p < 16; ++p) {
        int k = p * 4 + li;
        t[k][ln] = f2bf(src[(size_t)(tk + k) * 256 + tn + ln]);
    }
    __syncthreads();
    #pragma unroll
    for (int p = 0; p < 16; ++p) {
        int n = p * 4 + li;
        dst[(size_t)(tn + n) * 512 + koff + tk + ln] = t[ln][n];
    }
}

__device__ inline void gl16(const void* g, void* l) {
    __builtin_amdgcn_global_load_lds((const __attribute__((address_space(1))) void*)g,
                                     (__attribute__((address_space(3))) void*)l, 16, 0, 0);
}

// LDS byte offsets (dynamic smem)
#define RAW_OFF(buf) ((buf) * 53248)          // 2 x 52K  (50 instrs x 1KB used)
#define LW_OFF(buf)  (106496 + (buf) * 16384) // 2 x 16K
#define LAP_OFF      139264                   // 80 rows x 40 u16 (80B rows) = 6400
#define K1_LDS_BYTES 145664

__global__ __launch_bounds__(256, 1) void sage_k1(const float* __restrict__ h0,
                                                  const float* __restrict__ h1,
                                                  const float* __restrict__ h2,
                                                  const u16* __restrict__ W1t,
                                                  u16* __restrict__ nh1,
                                                  u16* __restrict__ nh0) {
    extern __shared__ __align__(16) char smem[];
    const int b = blockIdx.x;
    const int tid = threadIdx.x;
    const int lane = tid & 63;
    const int w = tid >> 6;

    const float* selfp; const float* nbrp; u16* dst;
    if (b < 1250) {
        selfp = h1 + (size_t)b * 80 * 256;
        nbrp  = h2 + (size_t)b * 800 * 256;
        dst   = nh1 + (size_t)b * 80 * 256;
    } else {
        int b2 = b - 1250;
        selfp = h0 + (size_t)b2 * 80 * 256;
        nbrp  = h1 + (size_t)b2 * 800 * 256;
        dst   = nh0 + (size_t)b2 * 80 * 256;
    }

    // issue the gl_lds batch for slice s2 (raw rows; plus W pair-slice on odd s2)
    auto stage = [&](int s2) {
        char* rbase = smem + RAW_OFF(s2 & 1);
        if (s2 < 16) {                       // self slice: 5 instrs (80 rows)
            int col0 = s2 * 16;
            int cnt = (w == 0) ? 2 : 1;
            for (int k = 0; k < cnt; ++k) {
                int i = (k == 0) ? w : 4;
                const float* g = selfp + (size_t)(i * 16 + (lane >> 2)) * 256
                                 + col0 + (lane & 3) * 4;
                gl16(g, rbase + i * 1024);
            }
        } else {                             // nbr slice: 50 instrs (800 rows)
            int col0 = (s2 - 16) * 16;
            int i0 = (w < 2) ? w * 13 : 26 + (w - 2) * 12;
            int cnt = (w < 2) ? 13 : 12;
            for (int k = 0; k < cnt; ++k) {
                int i = i0 + k;
                const float* g = nbrp + (size_t)(i * 16 + (lane >> 2)) * 256
                                 + col0 + (lane & 3) * 4;
                gl16(g, rbase + i * 1024);
            }
        }
        if (s2 & 1) {                        // W pair slice: 16 instrs (256 rows x 32k)
            int p2 = s2 >> 1;
            char* wbase = smem + LW_OFF(p2 & 1);
            for (int k = 0; k < 4; ++k) {
                int i = w * 4 + k;
                const u16* g = W1t + (size_t)(i * 16 + (lane >> 2)) * 512
                               + p2 * 32 + (lane & 3) * 8;
                gl16(g, wbase + i * 1024);
            }
        }
    };

    // wait until everything issued BEFORE batch s2 is complete (counted vmcnt)
    auto wait_before = [&](int s2) {
        if (s2 >= 32) {
            asm volatile("s_waitcnt vmcnt(0)" ::: "memory");
        } else if (s2 < 16) {
            if (s2 & 1) { if (w == 0) asm volatile("s_waitcnt vmcnt(6)" ::: "memory");
                          else        asm volatile("s_waitcnt vmcnt(5)" ::: "memory"); }
            else        { if (w == 0) asm volatile("s_waitcnt vmcnt(2)" ::: "memory");
                          else        asm volatile("s_waitcnt vmcnt(1)" ::: "memory"); }
        } else {
            if (s2 & 1) { if (w < 2) asm volatile("s_waitcnt vmcnt(17)" ::: "memory");
                          else       asm volatile("s_waitcnt vmcnt(16)" ::: "memory"); }
            else        { if (w < 2) asm volatile("s_waitcnt vmcnt(13)" ::: "memory");
                          else       asm volatile("s_waitcnt vmcnt(12)" ::: "memory"); }
        }
    };

    // prologue: fill the 2-deep pipeline
    stage(0);
    stage(1);
    wait_before(1);                     // raw(0) landed
    __builtin_amdgcn_s_barrier();

    f32x4 acc[5][4] = {};
    const int an = lane & 15;
    const int ak = (lane >> 4) * 8;
    const int cc = tid >> 4;            // consumer col 0..15
    const int ob = (tid & 15) * 5;      // consumer out-row base

    for (int s = 0; s < 32; ++s) {
        // ---- consume raw[s&1] -> lAp half (s&1)
        {
            const char* rb = smem + RAW_OFF(s & 1);
            u16* lap = (u16*)(smem + LAP_OFF);
            int hcol = (s & 1) * 16 + cc;
            if (s < 16) {
                #pragma unroll
                for (int q = 0; q < 5; ++q) {
                    int o = ob + q;
                    float v = *(const float*)(rb + ((o >> 4) * 1024 + (o & 15) * 64 + cc * 4));
                    lap[o * 40 + hcol] = f2bf(v);
                }
            } else {
                #pragma unroll
                for (int q = 0; q < 5; ++q) {
                    int o = ob + q;
                    float a = 0.f;
                    #pragma unroll
                    for (int j = 0; j < 10; ++j) {
                        int r = 10 * o + j;
                        a += *(const float*)(rb + ((r >> 4) * 1024 + (r & 15) * 64 + cc * 4));
                    }
                    lap[o * 40 + hcol] = f2bf(a * 0.1f);
                }
            }
        }
        // ---- odd slice: MFMA over the completed K=32 pair
        if (s & 1) {
            asm volatile("s_waitcnt lgkmcnt(0)" ::: "memory");
            __builtin_amdgcn_s_barrier();          // lAp complete (all waves)
            int p = s >> 1;
            const u16* lw = (const u16*)(smem + LW_OFF(p & 1));
            const u16* lap = (const u16*)(smem + LAP_OFF);
            s16x8 aF[5], bF[4];
            #pragma unroll
            for (int m = 0; m < 5; ++m)
                aF[m] = *(const s16x8*)(lap + (m * 16 + an) * 40 + ak);
            #pragma unroll
            for (int nn = 0; nn < 4; ++nn)
                bF[nn] = *(const s16x8*)(lw + (size_t)(w * 64 + nn * 16 + an) * 32 + ak);
            #pragma unroll
            for (int m = 0; m < 5; ++m)
                #pragma unroll
                for (int nn = 0; nn < 4; ++nn)
                    acc[m][nn] = __builtin_amdgcn_mfma_f32_16x16x32_bf16(aF[m], bF[nn], acc[m][nn], 0, 0, 0);
        }
        // ---- all LDS reads of raw[s&1]/lW done -> safe to re-stage that buffer
        asm volatile("s_waitcnt lgkmcnt(0)" ::: "memory");
        __builtin_amdgcn_s_barrier();
        if (s + 2 < 32) stage(s + 2);
        wait_before(s + 2);                        // raw(s+1) (+W) landed
        __builtin_amdgcn_s_barrier();
    }

    // ---- epilogue: relu -> bf16 -> nh.  C/D layout col=lane&15, row=(lane>>4)*4+j
    const int r0 = (lane >> 4) * 4;
    const int c0 = w * 64 + an;
    #pragma unroll
    for (int m = 0; m < 5; ++m)
        #pragma unroll
        for (int nn = 0; nn < 4; ++nn)
            #pragma unroll
            for (int j = 0; j < 4; ++j)
                dst[(size_t)(m * 16 + r0 + j) * 256 + c0 + nn * 16] =
                    f2bf(fmaxf(acc[m][nn][j], 0.f));
}

// ---- K2: layer 2 (round-5 proven 16-row tile) -----------------------------
__device__ inline void store_lA(u16* lA, int r, int c, u16x4 v) {   // c mult of 4
    int byte = c * 2, chunk = byte >> 4, off = byte & 15;
    *(u16x4*)((char*)(lA + (size_t)r * 512) + ((chunk ^ (r & 7)) * 16) + off) = v;
}
__device__ inline s16x8 read_lA(const u16* lA, int r, int k) {      // k mult of 8
    int chunk = (k * 2) >> 4;
    return *(const s16x8*)((const char*)(lA + (size_t)r * 512) + ((chunk ^ (r & 7)) * 16));
}

__global__ __launch_bounds__(256, 6) void sage_l2(const u16* __restrict__ nh0,
                                                  const u16* __restrict__ nh1,
                                                  const u16* __restrict__ W2t,
                                                  float* __restrict__ out) {
    __shared__ __align__(16) u16 lA[16 * 512];
    const int b = blockIdx.x;
    const int tid = threadIdx.x;
    const int lane = tid & 63;
    const int wave = tid >> 6;
    const int row0 = b * 16;

    // phase 0a: self (nh0) -> cols 0..255
    #pragma unroll
    for (int p = 0; p < 4; ++p) {
        int chunk = p * 256 + tid;
        int r = chunk >> 6;
        int c4 = (chunk & 63) * 4;
        u16x4 sb = *(const u16x4*)(nh0 + (size_t)(row0 + r) * 256 + c4);
        store_lA(lA, r, c4, sb);
    }
    // phase 0b: mean10(nh1) -> cols 256..511
    #pragma unroll
    for (int p = 0; p < 4; ++p) {
        int chunk = p * 256 + tid;
        int r = chunk >> 6;
        int c4 = (chunk & 63) * 4;
        const u16* nb = nh1 + (size_t)(row0 + r) * 10 * 256 + c4;
        float a[4] = {0.f, 0.f, 0.f, 0.f};
        #pragma unroll
        for (int j = 0; j < 10; ++j) {
            u16x4 v = *(const u16x4*)(nb + (size_t)j * 256);
            #pragma unroll
            for (int i = 0; i < 4; ++i) a[i] += bf2f(v[i]);
        }
        u16x4 mb;
        #pragma unroll
        for (int i = 0; i < 4; ++i) mb[i] = f2bf(a[i] * 0.1f);
        store_lA(lA, r, 256 + c4, mb);
    }
    __syncthreads();

    // K=512 MFMA; B direct from L2/L3
    f32x4 acc[4] = {};
    const int an = lane & 15;
    const int ak = (lane >> 4) * 8;
    const u16* bp[4];
    #pragma unroll
    for (int nn = 0; nn < 4; ++nn)
        bp[nn] = W2t + (size_t)(wave * 64 + nn * 16 + an) * 512 + ak;

    for (int kt = 0; kt < 8; ++kt) {
        const int kbase = kt * 64;
        s16x8 bF[2][4];
        #pragma unroll
        for (int ks = 0; ks < 2; ++ks)
            #pragma unroll
            for (int nn = 0; nn < 4; ++nn)
                bF[ks][nn] = *(const s16x8*)(bp[nn] + kbase + ks * 32);
        #pragma unroll
        for (int ks = 0; ks < 2; ++ks) {
            s16x8 aF = read_lA(lA, an, kbase + ks * 32 + ak);
            #pragma unroll
            for (int nn = 0; nn < 4; ++nn)
                acc[nn] = __builtin_amdgcn_mfma_f32_16x16x32_bf16(aF, bF[ks][nn], acc[nn], 0, 0, 0);
        }
    }

    const int r0 = (lane >> 4) * 4;
    const int c0 = wave * 64 + an;
    #pragma unroll
    for (int nn = 0; nn < 4; ++nn)
        #pragma unroll
        for (int j = 0; j < 4; ++j)
            out[(size_t)(row0 + r0 + j) * 256 + c0 + nn * 16] = acc[nn][j];
}

extern "C" void kernel_launch(void* const* d_in, const int* in_sizes, int n_in,
                              void* d_out, int out_size, void* d_ws, size_t ws_size,
                              hipStream_t stream) {
    const float* h0  = (const float*)d_in[0];
    const float* h1  = (const float*)d_in[1];
    const float* h2  = (const float*)d_in[2];
    const float* w1s = (const float*)d_in[3];
    const float* w1n = (const float*)d_in[4];
    const float* w2s = (const float*)d_in[5];
    const float* w2n = (const float*)d_in[6];

    char* ws = (char*)d_ws;
    u16* W1t = (u16*)ws; ws += (size_t)256 * 512 * 2;
    u16* W2t = (u16*)ws; ws += (size_t)256 * 512 * 2;
    u16* nh1 = (u16*)ws; ws += (size_t)100000 * 256 * 2;
    u16* nh0 = (u16*)ws; ws += (size_t)10000 * 256 * 2;
    (void)ws_size; (void)in_sizes; (void)n_in; (void)out_size;

    // allow 142 KB dynamic LDS (idempotent; host-side, graph-capture-safe)
    (void)hipFuncSetAttribute((const void*)sage_k1,
                              hipFuncAttributeMaxDynamicSharedMemorySize, K1_LDS_BYTES);

    conv_w2t<<<64, 256, 0, stream>>>(w1s, w1n, w2s, w2n, W1t, W2t);

    // layer 1: 1250 job1 blocks (h1|h2 -> nh1) + 125 job0 blocks (h0|h1 -> nh0)
    sage_k1<<<1375, 256, K1_LDS_BYTES, stream>>>(h0, h1, h2, W1t, nh1, nh0);

    // layer 2: out = [nh0 | mean10(nh1)] @ W2t^T, f32
    sage_l2<<<625, 256, 0, stream>>>(nh0, nh1, W2t, (float*)d_out);
}

// Round 10
// 511.308 us; speedup vs baseline: 1.0018x; 1.0018x over previous
//
#include <hip/hip_runtime.h>
#include <stdint.h>

// GraphSAGE on MI355X — round 8: fire-and-forget staging.
// Theory: rounds 2-7 all capped at ~4.1 TB/s effective read BW because
// register-staged loads limit per-CU in-flight bytes (Little's law needs
// ~9.5 KB/CU; VGPR-windowed loads give ~5-6 KB). Fix: global_load_lds +
// counted s_waitcnt vmcnt(N) (T3/T4) — payload bypasses VGPRs, loads stay
// outstanding across barriers.
//
//  K1 (sage_k1): layer 1, BM=80 rows/block (1250 job1 + 125 job0 blocks, exact).
//    K=512 in 32 slices of 16 cols. Per slice s:
//      consume raw[s&1] (mean10 / convert) -> lAp half   [LDS only]
//      s odd: barrier; MFMA K=32 (A from lAp, B from lW[p&1])  [LDS only]
//      barrier; issue gl_lds stage(s+2): raw rows + (odd) W1t k-slice
//      s_waitcnt vmcnt(I(s+2))  -- counted, never drains pipeline
//      barrier
//    LDS: raw dbuf 2x52K + lW dbuf 2x16K + lAp 6.4K = 142.25 KB (dynamic).
//  K2 (sage_l2): layer 2, round-5's proven 16-row tile kernel.

typedef unsigned short u16;
typedef __attribute__((ext_vector_type(4))) float f32x4;
typedef __attribute__((ext_vector_type(8))) short s16x8;
typedef __attribute__((ext_vector_type(4))) unsigned short u16x4;

__device__ inline u16 f2bf(float x) {
    union { float f; uint32_t u; } v; v.f = x;
    uint32_t b = v.u;
    b += 0x7FFFu + ((b >> 16) & 1u);   // round-to-nearest-even
    return (u16)(b >> 16);
}
__device__ inline float bf2f(u16 u) {
    union { uint32_t u; float f; } v; v.u = ((uint32_t)u) << 16;
    return v.f;
}

// Transposed bf16 weight build: dst[n][koff+k] = f2bf(src[k][n]), 64x64 tiles.
__global__ __launch_bounds__(256) void conv_w2t(const float* __restrict__ w1s,
                                                const float* __restrict__ w1n,
                                                const float* __restrict__ w2s,
                                                const float* __restrict__ w2n,
                                                u16* __restrict__ W1t,
                                                u16* __restrict__ W2t) {
    __shared__ u16 t[64][66];
    const int b = blockIdx.x;
    const int mat = b >> 4;
    const int tk = ((b >> 2) & 3) * 64;
    const int tn = (b & 3) * 64;
    const float* src = (mat == 0) ? w1s : (mat == 1) ? w1n : (mat == 2) ? w2s : w2n;
    u16* dst = (mat < 2) ? W1t : W2t;
    const int koff = (mat & 1) * 256;
    const int tid = threadIdx.x;
    const int li = tid >> 6, ln = tid & 63;
    #pragma unroll
    for (int p = 0; p < 16; ++p) {
        int k = p * 4 + li;
        t[k][ln] = f2bf(src[(size_t)(tk + k) * 256 + tn + ln]);
    }
    __syncthreads();
    #pragma unroll
    for (int p = 0; p < 16; ++p) {
        int n = p * 4 + li;
        dst[(size_t)(tn + n) * 512 + koff + tk + ln] = t[ln][n];
    }
}

__device__ inline void gl16(const void* g, void* l) {
    __builtin_amdgcn_global_load_lds((const __attribute__((address_space(1))) void*)g,
                                     (__attribute__((address_space(3))) void*)l, 16, 0, 0);
}

// LDS byte offsets (dynamic smem)
#define RAW_OFF(buf) ((buf) * 53248)          // 2 x 52K  (50 instrs x 1KB used)
#define LW_OFF(buf)  (106496 + (buf) * 16384) // 2 x 16K
#define LAP_OFF      139264                   // 80 rows x 40 u16 (80B rows) = 6400
#define K1_LDS_BYTES 145664

__global__ __launch_bounds__(256, 1) void sage_k1(const float* __restrict__ h0,
                                                  const float* __restrict__ h1,
                                                  const float* __restrict__ h2,
                                                  const u16* __restrict__ W1t,
                                                  u16* __restrict__ nh1,
                                                  u16* __restrict__ nh0) {
    extern __shared__ __align__(16) char smem[];
    const int b = blockIdx.x;
    const int tid = threadIdx.x;
    const int lane = tid & 63;
    const int w = tid >> 6;

    const float* selfp; const float* nbrp; u16* dst;
    if (b < 1250) {
        selfp = h1 + (size_t)b * 80 * 256;
        nbrp  = h2 + (size_t)b * 800 * 256;
        dst   = nh1 + (size_t)b * 80 * 256;
    } else {
        int b2 = b - 1250;
        selfp = h0 + (size_t)b2 * 80 * 256;
        nbrp  = h1 + (size_t)b2 * 800 * 256;
        dst   = nh0 + (size_t)b2 * 80 * 256;
    }

    // issue the gl_lds batch for slice s2 (raw rows; plus W pair-slice on odd s2)
    auto stage = [&](int s2) {
        char* rbase = smem + RAW_OFF(s2 & 1);
        if (s2 < 16) {                       // self slice: 5 instrs (80 rows)
            int col0 = s2 * 16;
            int cnt = (w == 0) ? 2 : 1;
            for (int k = 0; k < cnt; ++k) {
                int i = (k == 0) ? w : 4;
                const float* g = selfp + (size_t)(i * 16 + (lane >> 2)) * 256
                                 + col0 + (lane & 3) * 4;
                gl16(g, rbase + i * 1024);
            }
        } else {                             // nbr slice: 50 instrs (800 rows)
            int col0 = (s2 - 16) * 16;
            int i0 = (w < 2) ? w * 13 : 26 + (w - 2) * 12;
            int cnt = (w < 2) ? 13 : 12;
            for (int k = 0; k < cnt; ++k) {
                int i = i0 + k;
                const float* g = nbrp + (size_t)(i * 16 + (lane >> 2)) * 256
                                 + col0 + (lane & 3) * 4;
                gl16(g, rbase + i * 1024);
            }
        }
        if (s2 & 1) {                        // W pair slice: 16 instrs (256 rows x 32k)
            int p2 = s2 >> 1;
            char* wbase = smem + LW_OFF(p2 & 1);
            for (int k = 0; k < 4; ++k) {
                int i = w * 4 + k;
                const u16* g = W1t + (size_t)(i * 16 + (lane >> 2)) * 512
                               + p2 * 32 + (lane & 3) * 8;
                gl16(g, wbase + i * 1024);
            }
        }
    };

    // wait until everything issued BEFORE batch s2 is complete (counted vmcnt)
    auto wait_before = [&](int s2) {
        if (s2 >= 32) {
            asm volatile("s_waitcnt vmcnt(0)" ::: "memory");
        } else if (s2 < 16) {
            if (s2 & 1) { if (w == 0) asm volatile("s_waitcnt vmcnt(6)" ::: "memory");
                          else        asm volatile("s_waitcnt vmcnt(5)" ::: "memory"); }
            else        { if (w == 0) asm volatile("s_waitcnt vmcnt(2)" ::: "memory");
                          else        asm volatile("s_waitcnt vmcnt(1)" ::: "memory"); }
        } else {
            if (s2 & 1) { if (w < 2) asm volatile("s_waitcnt vmcnt(17)" ::: "memory");
                          else       asm volatile("s_waitcnt vmcnt(16)" ::: "memory"); }
            else        { if (w < 2) asm volatile("s_waitcnt vmcnt(13)" ::: "memory");
                          else       asm volatile("s_waitcnt vmcnt(12)" ::: "memory"); }
        }
    };

    // prologue: fill the 2-deep pipeline
    stage(0);
    stage(1);
    wait_before(1);                     // raw(0) landed
    __builtin_amdgcn_s_barrier();

    f32x4 acc[5][4] = {};
    const int an = lane & 15;
    const int ak = (lane >> 4) * 8;
    const int cc = tid >> 4;            // consumer col 0..15
    const int ob = (tid & 15) * 5;      // consumer out-row base

    for (int s = 0; s < 32; ++s) {
        // ---- consume raw[s&1] -> lAp half (s&1)
        {
            const char* rb = smem + RAW_OFF(s & 1);
            u16* lap = (u16*)(smem + LAP_OFF);
            int hcol = (s & 1) * 16 + cc;
            if (s < 16) {
                #pragma unroll
                for (int q = 0; q < 5; ++q) {
                    int o = ob + q;
                    float v = *(const float*)(rb + ((o >> 4) * 1024 + (o & 15) * 64 + cc * 4));
                    lap[o * 40 + hcol] = f2bf(v);
                }
            } else {
                #pragma unroll
                for (int q = 0; q < 5; ++q) {
                    int o = ob + q;
                    float a = 0.f;
                    #pragma unroll
                    for (int j = 0; j < 10; ++j) {
                        int r = 10 * o + j;
                        a += *(const float*)(rb + ((r >> 4) * 1024 + (r & 15) * 64 + cc * 4));
                    }
                    lap[o * 40 + hcol] = f2bf(a * 0.1f);
                }
            }
        }
        // ---- odd slice: MFMA over the completed K=32 pair
        if (s & 1) {
            asm volatile("s_waitcnt lgkmcnt(0)" ::: "memory");
            __builtin_amdgcn_s_barrier();          // lAp complete (all waves)
            int p = s >> 1;
            const u16* lw = (const u16*)(smem + LW_OFF(p & 1));
            const u16* lap = (const u16*)(smem + LAP_OFF);
            s16x8 aF[5], bF[4];
            #pragma unroll
            for (int m = 0; m < 5; ++m)
                aF[m] = *(const s16x8*)(lap + (m * 16 + an) * 40 + ak);
            #pragma unroll
            for (int nn = 0; nn < 4; ++nn)
                bF[nn] = *(const s16x8*)(lw + (size_t)(w * 64 + nn * 16 + an) * 32 + ak);
            #pragma unroll
            for (int m = 0; m < 5; ++m)
                #pragma unroll
                for (int nn = 0; nn < 4; ++nn)
                    acc[m][nn] = __builtin_amdgcn_mfma_f32_16x16x32_bf16(aF[m], bF[nn], acc[m][nn], 0, 0, 0);
        }
        // ---- all LDS reads of raw[s&1]/lW done -> safe to re-stage that buffer
        asm volatile("s_waitcnt lgkmcnt(0)" ::: "memory");
        __builtin_amdgcn_s_barrier();
        if (s + 2 < 32) stage(s + 2);
        wait_before(s + 2);                        // raw(s+1) (+W) landed
        __builtin_amdgcn_s_barrier();
    }

    // ---- epilogue: relu -> bf16 -> nh.  C/D layout col=lane&15, row=(lane>>4)*4+j
    const int r0 = (lane >> 4) * 4;
    const int c0 = w * 64 + an;
    #pragma unroll
    for (int m = 0; m < 5; ++m)
        #pragma unroll
        for (int nn = 0; nn < 4; ++nn)
            #pragma unroll
            for (int j = 0; j < 4; ++j)
                dst[(size_t)(m * 16 + r0 + j) * 256 + c0 + nn * 16] =
                    f2bf(fmaxf(acc[m][nn][j], 0.f));
}

// ---- K2: layer 2 (round-5 proven 16-row tile) -----------------------------
__device__ inline void store_lA(u16* lA, int r, int c, u16x4 v) {   // c mult of 4
    int byte = c * 2, chunk = byte >> 4, off = byte & 15;
    *(u16x4*)((char*)(lA + (size_t)r * 512) + ((chunk ^ (r & 7)) * 16) + off) = v;
}
__device__ inline s16x8 read_lA(const u16* lA, int r, int k) {      // k mult of 8
    int chunk = (k * 2) >> 4;
    return *(const s16x8*)((const char*)(lA + (size_t)r * 512) + ((chunk ^ (r & 7)) * 16));
}

__global__ __launch_bounds__(256, 6) void sage_l2(const u16* __restrict__ nh0,
                                                  const u16* __restrict__ nh1,
                                                  const u16* __restrict__ W2t,
                                                  float* __restrict__ out) {
    __shared__ __align__(16) u16 lA[16 * 512];
    const int b = blockIdx.x;
    const int tid = threadIdx.x;
    const int lane = tid & 63;
    const int wave = tid >> 6;
    const int row0 = b * 16;

    // phase 0a: self (nh0) -> cols 0..255
    #pragma unroll
    for (int p = 0; p < 4; ++p) {
        int chunk = p * 256 + tid;
        int r = chunk >> 6;
        int c4 = (chunk & 63) * 4;
        u16x4 sb = *(const u16x4*)(nh0 + (size_t)(row0 + r) * 256 + c4);
        store_lA(lA, r, c4, sb);
    }
    // phase 0b: mean10(nh1) -> cols 256..511
    #pragma unroll
    for (int p = 0; p < 4; ++p) {
        int chunk = p * 256 + tid;
        int r = chunk >> 6;
        int c4 = (chunk & 63) * 4;
        const u16* nb = nh1 + (size_t)(row0 + r) * 10 * 256 + c4;
        float a[4] = {0.f, 0.f, 0.f, 0.f};
        #pragma unroll
        for (int j = 0; j < 10; ++j) {
            u16x4 v = *(const u16x4*)(nb + (size_t)j * 256);
            #pragma unroll
            for (int i = 0; i < 4; ++i) a[i] += bf2f(v[i]);
        }
        u16x4 mb;
        #pragma unroll
        for (int i = 0; i < 4; ++i) mb[i] = f2bf(a[i] * 0.1f);
        store_lA(lA, r, 256 + c4, mb);
    }
    __syncthreads();

    // K=512 MFMA; B direct from L2/L3
    f32x4 acc[4] = {};
    const int an = lane & 15;
    const int ak = (lane >> 4) * 8;
    const u16* bp[4];
    #pragma unroll
    for (int nn = 0; nn < 4; ++nn)
        bp[nn] = W2t + (size_t)(wave * 64 + nn * 16 + an) * 512 + ak;

    for (int kt = 0; kt < 8; ++kt) {
        const int kbase = kt * 64;
        s16x8 bF[2][4];
        #pragma unroll
        for (int ks = 0; ks < 2; ++ks)
            #pragma unroll
            for (int nn = 0; nn < 4; ++nn)
                bF[ks][nn] = *(const s16x8*)(bp[nn] + kbase + ks * 32);
        #pragma unroll
        for (int ks = 0; ks < 2; ++ks) {
            s16x8 aF = read_lA(lA, an, kbase + ks * 32 + ak);
            #pragma unroll
            for (int nn = 0; nn < 4; ++nn)
                acc[nn] = __builtin_amdgcn_mfma_f32_16x16x32_bf16(aF, bF[ks][nn], acc[nn], 0, 0, 0);
        }
    }

    const int r0 = (lane >> 4) * 4;
    const int c0 = wave * 64 + an;
    #pragma unroll
    for (int nn = 0; nn < 4; ++nn)
        #pragma unroll
        for (int j = 0; j < 4; ++j)
            out[(size_t)(row0 + r0 + j) * 256 + c0 + nn * 16] = acc[nn][j];
}

extern "C" void kernel_launch(void* const* d_in, const int* in_sizes, int n_in,
                              void* d_out, int out_size, void* d_ws, size_t ws_size,
                              hipStream_t stream) {
    const float* h0  = (const float*)d_in[0];
    const float* h1  = (const float*)d_in[1];
    const float* h2  = (const float*)d_in[2];
    const float* w1s = (const float*)d_in[3];
    const float* w1n = (const float*)d_in[4];
    const float* w2s = (const float*)d_in[5];
    const float* w2n = (const float*)d_in[6];

    char* ws = (char*)d_ws;
    u16* W1t = (u16*)ws; ws += (size_t)256 * 512 * 2;
    u16* W2t = (u16*)ws; ws += (size_t)256 * 512 * 2;
    u16* nh1 = (u16*)ws; ws += (size_t)100000 * 256 * 2;
    u16* nh0 = (u16*)ws; ws += (size_t)10000 * 256 * 2;
    (void)ws_size; (void)in_sizes; (void)n_in; (void)out_size;

    // allow 142 KB dynamic LDS (idempotent; host-side, graph-capture-safe)
    (void)hipFuncSetAttribute((const void*)sage_k1,
                              hipFuncAttributeMaxDynamicSharedMemorySize, K1_LDS_BYTES);

    conv_w2t<<<64, 256, 0, stream>>>(w1s, w1n, w2s, w2n, W1t, W2t);

    // layer 1: 1250 job1 blocks (h1|h2 -> nh1) + 125 job0 blocks (h0|h1 -> nh0)
    sage_k1<<<1375, 256, K1_LDS_BYTES, stream>>>(h0, h1, h2, W1t, nh1, nh0);

    // layer 2: out = [nh0 | mean10(nh1)] @ W2t^T, f32
    sage_l2<<<625, 256, 0, stream>>>(nh0, nh1, W2t, (float*)d_out);
}

// Round 11
// 340.075 us; speedup vs baseline: 1.5063x; 1.5035x over previous
//
#include <hip/hip_runtime.h>
#include <stdint.h>

// GraphSAGE on MI355X — round 9: split the dominant stream into a 100%-duty kernel.
//   conv_w2t : W1t[256][512]=[w1s;w1n]^T bf16, W2t likewise
//   mean10_k : m2[100000][256] = bf16(mean10(h2)) ; m1[10000][256] = bf16(mean10(h1))
//              pure streaming (no LDS/barriers, 10KB contiguous burst per wave)
//   sage_l1  : merged layer 1 (ROWS=64 tiles):
//                job0: nh1 = relu([h1 | m2] @ W1t^T)   1563 blocks
//                job1: nh0 = relu([h0 | m1] @ W1t^T)    157 blocks
//   sage_l2  : out = [nh0 | mean10(nh1)] @ W2t^T  f32   625 blocks (16-row tiles)
// Rationale: rounds 2-7 plateaued at ~4.2 TB/s effective = 6.5 TB/s x ~65%
// HBM-phase duty (lockstep block phases). mean10_k carries 78% of all traffic
// at (predicted) full streaming rate.

typedef unsigned short u16;
typedef __attribute__((ext_vector_type(4))) float f32x4;
typedef __attribute__((ext_vector_type(8))) short s16x8;
typedef __attribute__((ext_vector_type(4))) unsigned short u16x4;

__device__ inline u16 f2bf(float x) {
    union { float f; uint32_t u; } v; v.f = x;
    uint32_t b = v.u;
    b += 0x7FFFu + ((b >> 16) & 1u);   // round-to-nearest-even
    return (u16)(b >> 16);
}
__device__ inline float bf2f(u16 u) {
    union { uint32_t u; float f; } v; v.u = ((uint32_t)u) << 16;
    return v.f;
}

// Transposed bf16 weight build: dst[n][koff+k] = f2bf(src[k][n]), 64x64 tiles.
__global__ __launch_bounds__(256) void conv_w2t(const float* __restrict__ w1s,
                                                const float* __restrict__ w1n,
                                                const float* __restrict__ w2s,
                                                const float* __restrict__ w2n,
                                                u16* __restrict__ W1t,
                                                u16* __restrict__ W2t) {
    __shared__ u16 t[64][66];
    const int b = blockIdx.x;
    const int mat = b >> 4;
    const int tk = ((b >> 2) & 3) * 64;
    const int tn = (b & 3) * 64;
    const float* src = (mat == 0) ? w1s : (mat == 1) ? w1n : (mat == 2) ? w2s : w2n;
    u16* dst = (mat < 2) ? W1t : W2t;
    const int koff = (mat & 1) * 256;
    const int tid = threadIdx.x;
    const int li = tid >> 6, ln = tid & 63;
    #pragma unroll
    for (int p = 0; p < 16; ++p) {
        int k = p * 4 + li;
        t[k][ln] = f2bf(src[(size_t)(tk + k) * 256 + tn + ln]);
    }
    __syncthreads();
    #pragma unroll
    for (int p = 0; p < 16; ++p) {
        int n = p * 4 + li;
        dst[(size_t)(tn + n) * 512 + koff + tk + ln] = t[ln][n];
    }
}

// Pure-streaming neighbor mean: one wave per output row, 10 x f32x4 loads
// (contiguous 10KB burst), f32 accumulate, bf16 store. rows 0..99999 -> m2
// (from h2), rows 100000..109999 -> m1 (from h1). Grid 27500 x 4 waves exact.
__global__ __launch_bounds__(256) void mean10_k(const float* __restrict__ h2,
                                                const float* __restrict__ h1,
                                                u16* __restrict__ m2,
                                                u16* __restrict__ m1) {
    const int row = blockIdx.x * 4 + (threadIdx.x >> 6);
    const int lane = threadIdx.x & 63;
    const float* src; u16* dst;
    if (row < 100000) { src = h2 + (size_t)row * 2560;            dst = m2 + (size_t)row * 256; }
    else              { int r = row - 100000;
                        src = h1 + (size_t)r * 2560;              dst = m1 + (size_t)r * 256; }
    const int c = lane * 4;
    f32x4 acc = {0.f, 0.f, 0.f, 0.f};
    #pragma unroll
    for (int j = 0; j < 10; ++j)
        acc += *(const f32x4*)(src + j * 256 + c);
    u16x4 o;
    #pragma unroll
    for (int i = 0; i < 4; ++i) o[i] = f2bf(acc[i] * 0.1f);
    *(u16x4*)(dst + c) = o;
}

// ---- swizzled LDS A-tile: lA[ROWS][512] bf16, 1024 B/row, 64 16B-chunks/row
// physical chunk = logical chunk ^ (row & 7)
__device__ inline void store_lA(u16* lA, int r, int c, u16x4 v) {   // c mult of 4
    int byte = c * 2, chunk = byte >> 4, off = byte & 15;
    *(u16x4*)((char*)(lA + (size_t)r * 512) + ((chunk ^ (r & 7)) * 16) + off) = v;
}
__device__ inline s16x8 read_lA(const u16* lA, int r, int k) {      // k mult of 8
    int chunk = (k * 2) >> 4;
    return *(const s16x8*)((const char*)(lA + (size_t)r * 512) + ((chunk ^ (r & 7)) * 16));
}

// Merged layer 1: ROWS=64 tiles; job0 = (h1|m2)->nh1, job1 = (h0|m1)->nh0.
// Self half is f32 (convert); neighbor half is PRE-MEANED bf16 (copy).
__global__ __launch_bounds__(256, 2) void sage_l1(const float* __restrict__ s0,
                                                  const u16* __restrict__ m0,
                                                  u16* __restrict__ o0, int nrow0, int nblk0,
                                                  const float* __restrict__ s1,
                                                  const u16* __restrict__ m1p,
                                                  u16* __restrict__ o1, int nrow1,
                                                  const u16* __restrict__ Bt) {
    __shared__ __align__(16) u16 lA[64 * 512];     // 64 KB
    const int b = blockIdx.x;
    const float* selfp; const u16* meanp; u16* outp; int row0; int nrows;
    if (b < nblk0) { selfp = s0; meanp = m0;  outp = o0; row0 = b * 64;           nrows = nrow0; }
    else           { selfp = s1; meanp = m1p; outp = o1; row0 = (b - nblk0) * 64; nrows = nrow1; }

    const int tid = threadIdx.x;
    const int lane = tid & 63;
    const int wave = tid >> 6;

    // phase 0a: self (f32 -> bf16) -> cols 0..255   (64 rows x 64 chunks; 16/thread)
    #pragma unroll
    for (int p = 0; p < 16; ++p) {
        int chunk = p * 256 + tid;
        int r = chunk >> 6;
        int c4 = (chunk & 63) * 4;
        int gr = min(row0 + r, nrows - 1);
        f32x4 v = *(const f32x4*)(selfp + (size_t)gr * 256 + c4);
        u16x4 sb;
        #pragma unroll
        for (int i = 0; i < 4; ++i) sb[i] = f2bf(v[i]);
        store_lA(lA, r, c4, sb);
    }
    // phase 0b: pre-meaned neighbor (bf16 copy) -> cols 256..511
    #pragma unroll
    for (int p = 0; p < 16; ++p) {
        int chunk = p * 256 + tid;
        int r = chunk >> 6;
        int c4 = (chunk & 63) * 4;
        int gr = min(row0 + r, nrows - 1);
        u16x4 mb = *(const u16x4*)(meanp + (size_t)gr * 256 + c4);
        store_lA(lA, r, 256 + c4, mb);
    }
    __syncthreads();

    // K=512 MFMA; B fragments straight from L2 (weights resident)
    f32x4 acc[4][4] = {};
    const int an = lane & 15;
    const int ak = (lane >> 4) * 8;
    const u16* bp[4];
    #pragma unroll
    for (int nn = 0; nn < 4; ++nn)
        bp[nn] = Bt + (size_t)(wave * 64 + nn * 16 + an) * 512 + ak;

    for (int kt = 0; kt < 8; ++kt) {
        const int kbase = kt * 64;
        s16x8 bF[2][4];
        #pragma unroll
        for (int ks = 0; ks < 2; ++ks)
            #pragma unroll
            for (int nn = 0; nn < 4; ++nn)
                bF[ks][nn] = *(const s16x8*)(bp[nn] + kbase + ks * 32);
        #pragma unroll
        for (int ks = 0; ks < 2; ++ks) {
            s16x8 aF[4];
            #pragma unroll
            for (int m = 0; m < 4; ++m)
                aF[m] = read_lA(lA, m * 16 + an, kbase + ks * 32 + ak);
            #pragma unroll
            for (int m = 0; m < 4; ++m)
                #pragma unroll
                for (int nn = 0; nn < 4; ++nn)
                    acc[m][nn] = __builtin_amdgcn_mfma_f32_16x16x32_bf16(aF[m], bF[ks][nn], acc[m][nn], 0, 0, 0);
        }
    }

    // epilogue: relu -> bf16. C/D layout col=lane&15, row=(lane>>4)*4+j [m89]
    const int r0 = (lane >> 4) * 4;
    const int c0 = wave * 64 + an;
    #pragma unroll
    for (int m = 0; m < 4; ++m)
        #pragma unroll
        for (int nn = 0; nn < 4; ++nn)
            #pragma unroll
            for (int j = 0; j < 4; ++j) {
                int r = row0 + m * 16 + r0 + j;
                if (r < nrows)
                    outp[(size_t)r * 256 + c0 + nn * 16] = f2bf(fmaxf(acc[m][nn][j], 0.f));
            }
}

// Layer 2: 16-row tiles (round-5 proven): out = [nh0 | mean10(nh1)] @ W2t^T, f32.
__global__ __launch_bounds__(256, 6) void sage_l2(const u16* __restrict__ nh0,
                                                  const u16* __restrict__ nh1,
                                                  const u16* __restrict__ W2t,
                                                  float* __restrict__ out) {
    __shared__ __align__(16) u16 lA[16 * 512];
    const int b = blockIdx.x;
    const int tid = threadIdx.x;
    const int lane = tid & 63;
    const int wave = tid >> 6;
    const int row0 = b * 16;

    #pragma unroll
    for (int p = 0; p < 4; ++p) {
        int chunk = p * 256 + tid;
        int r = chunk >> 6;
        int c4 = (chunk & 63) * 4;
        u16x4 sb = *(const u16x4*)(nh0 + (size_t)(row0 + r) * 256 + c4);
        store_lA(lA, r, c4, sb);
    }
    #pragma unroll
    for (int p = 0; p < 4; ++p) {
        int chunk = p * 256 + tid;
        int r = chunk >> 6;
        int c4 = (chunk & 63) * 4;
        const u16* nb = nh1 + (size_t)(row0 + r) * 10 * 256 + c4;
        float a[4] = {0.f, 0.f, 0.f, 0.f};
        #pragma unroll
        for (int j = 0; j < 10; ++j) {
            u16x4 v = *(const u16x4*)(nb + (size_t)j * 256);
            #pragma unroll
            for (int i = 0; i < 4; ++i) a[i] += bf2f(v[i]);
        }
        u16x4 mb;
        #pragma unroll
        for (int i = 0; i < 4; ++i) mb[i] = f2bf(a[i] * 0.1f);
        store_lA(lA, r, 256 + c4, mb);
    }
    __syncthreads();

    f32x4 acc[4] = {};
    const int an = lane & 15;
    const int ak = (lane >> 4) * 8;
    const u16* bp[4];
    #pragma unroll
    for (int nn = 0; nn < 4; ++nn)
        bp[nn] = W2t + (size_t)(wave * 64 + nn * 16 + an) * 512 + ak;

    for (int kt = 0; kt < 8; ++kt) {
        const int kbase = kt * 64;
        s16x8 bF[2][4];
        #pragma unroll
        for (int ks = 0; ks < 2; ++ks)
            #pragma unroll
            for (int nn = 0; nn < 4; ++nn)
                bF[ks][nn] = *(const s16x8*)(bp[nn] + kbase + ks * 32);
        #pragma unroll
        for (int ks = 0; ks < 2; ++ks) {
            s16x8 aF = read_lA(lA, an, kbase + ks * 32 + ak);
            #pragma unroll
            for (int nn = 0; nn < 4; ++nn)
                acc[nn] = __builtin_amdgcn_mfma_f32_16x16x32_bf16(aF, bF[ks][nn], acc[nn], 0, 0, 0);
        }
    }

    const int r0 = (lane >> 4) * 4;
    const int c0 = wave * 64 + an;
    #pragma unroll
    for (int nn = 0; nn < 4; ++nn)
        #pragma unroll
        for (int j = 0; j < 4; ++j)
            out[(size_t)(row0 + r0 + j) * 256 + c0 + nn * 16] = acc[nn][j];
}

extern "C" void kernel_launch(void* const* d_in, const int* in_sizes, int n_in,
                              void* d_out, int out_size, void* d_ws, size_t ws_size,
                              hipStream_t stream) {
    const float* h0  = (const float*)d_in[0];
    const float* h1  = (const float*)d_in[1];
    const float* h2  = (const float*)d_in[2];
    const float* w1s = (const float*)d_in[3];
    const float* w1n = (const float*)d_in[4];
    const float* w2s = (const float*)d_in[5];
    const float* w2n = (const float*)d_in[6];

    char* ws = (char*)d_ws;
    u16* W1t = (u16*)ws; ws += (size_t)256 * 512 * 2;
    u16* W2t = (u16*)ws; ws += (size_t)256 * 512 * 2;
    u16* m2  = (u16*)ws; ws += (size_t)100000 * 256 * 2;
    u16* m1  = (u16*)ws; ws += (size_t)10000 * 256 * 2;
    u16* nh1 = (u16*)ws; ws += (size_t)100000 * 256 * 2;
    u16* nh0 = (u16*)ws; ws += (size_t)10000 * 256 * 2;
    (void)ws_size; (void)in_sizes; (void)n_in; (void)out_size;

    conv_w2t<<<64, 256, 0, stream>>>(w1s, w1n, w2s, w2n, W1t, W2t);

    // neighbor means: 100000 m2-rows + 10000 m1-rows = 110000 = 27500 x 4 waves
    mean10_k<<<27500, 256, 0, stream>>>(h2, h1, m2, m1);

    // merged layer 1: job0 = hop-1 (1563 blocks), job1 = hop-0 (157 blocks)
    sage_l1<<<1563 + 157, 256, 0, stream>>>(
        h1, m2, nh1, 100000, 1563,
        h0, m1, nh0, 10000, W1t);

    // layer 2: 625 x 16-row tiles
    sage_l2<<<625, 256, 0, stream>>>(nh0, nh1, W2t, (float*)d_out);
}

// Round 12
// 276.460 us; speedup vs baseline: 1.8529x; 1.2301x over previous
//
#include <hip/hip_runtime.h>
#include <stdint.h>

// GraphSAGE on MI355X — round 10: round-7 fused kernel + NON-TEMPORAL h2 loads.
// A/B experiment: R2-R9 all plateau at ~4.0-4.4 TB/s effective read BW (even a
// pure streaming mean kernel), while pure writes hit 6.5 TB/s. Hypothesis: the
// 1 GB h2 stream write-allocates into L2/MALL, and the miss/evict path throttles
// reads. Fix under test: __builtin_nontemporal_load on h2 (never-reused stream).
// Everything else identical to round-7 (284.4 µs baseline).
//
//   phase0 : lA[48][512] = { r<40 : bf16(h1[40b+r]) | bf16(mean10 h2-rows) [NT]
//                            r<44 : bf16(h0[4b+r-40]) | bf16(mean10 h1-rows)
//                            else zero }
//   layer1 : lA @ W1t^T (K=512 MFMA) -> sync -> relu -> bf16 lNH[48][256]
//   phase2 : lA2[16][512] := [ lNH[40+r] | mean10(lNH[10r..10r+9]) ], pad zero
//   layer2 : lA2 @ W2t^T -> f32 d_out rows 4b..4b+3
// LDS overlay: 48 KB total -> 3 blocks/CU.

typedef unsigned short u16;
typedef __attribute__((ext_vector_type(4))) float f32x4;
typedef __attribute__((ext_vector_type(8))) short s16x8;
typedef __attribute__((ext_vector_type(4))) unsigned short u16x4;

__device__ inline u16 f2bf(float x) {
    union { float f; uint32_t u; } v; v.f = x;
    uint32_t b = v.u;
    b += 0x7FFFu + ((b >> 16) & 1u);   // round-to-nearest-even
    return (u16)(b >> 16);
}
__device__ inline float bf2f(u16 u) {
    union { uint32_t u; float f; } v; v.u = ((uint32_t)u) << 16;
    return v.f;
}

// Transposed bf16 weight build: dst[n][koff+k] = f2bf(src[k][n]), 64x64 tiles.
__global__ __launch_bounds__(256) void conv_w2t(const float* __restrict__ w1s,
                                                const float* __restrict__ w1n,
                                                const float* __restrict__ w2s,
                                                const float* __restrict__ w2n,
                                                u16* __restrict__ W1t,
                                                u16* __restrict__ W2t) {
    __shared__ u16 t[64][66];
    const int b = blockIdx.x;
    const int mat = b >> 4;
    const int tk = ((b >> 2) & 3) * 64;
    const int tn = (b & 3) * 64;
    const float* src = (mat == 0) ? w1s : (mat == 1) ? w1n : (mat == 2) ? w2s : w2n;
    u16* dst = (mat < 2) ? W1t : W2t;
    const int koff = (mat & 1) * 256;
    const int tid = threadIdx.x;
    const int li = tid >> 6, ln = tid & 63;
    #pragma unroll
    for (int p = 0; p < 16; ++p) {
        int k = p * 4 + li;
        t[k][ln] = f2bf(src[(size_t)(tk + k) * 256 + tn + ln]);
    }
    __syncthreads();
    #pragma unroll
    for (int p = 0; p < 16; ++p) {
        int n = p * 4 + li;
        dst[(size_t)(tn + n) * 512 + koff + tk + ln] = t[ln][n];
    }
}

// ---- swizzled LDS tiles. Row = ROWLEN u16; 16B chunks; phys = chunk ^ (r&7).
__device__ inline void storeA(u16* t, int r, int c, u16x4 v) {      // ROWLEN 512
    int byte = c * 2, chunk = byte >> 4, off = byte & 15;
    *(u16x4*)((char*)(t + (size_t)r * 512) + ((chunk ^ (r & 7)) * 16) + off) = v;
}
__device__ inline s16x8 readA8(const u16* t, int r, int k) {        // 16B, k mult 8
    int chunk = (k * 2) >> 4;
    return *(const s16x8*)((const char*)(t + (size_t)r * 512) + ((chunk ^ (r & 7)) * 16));
}
__device__ inline void storeNH1(u16* t, int r, int c, u16 v) {      // ROWLEN 256
    int byte = c * 2, chunk = byte >> 4, off = byte & 15;
    *(u16*)((char*)(t + (size_t)r * 256) + ((chunk ^ (r & 7)) * 16) + off) = v;
}
__device__ inline u16x4 readNH4(const u16* t, int r, int c) {       // 8B, c mult 4
    int byte = c * 2, chunk = byte >> 4, off = byte & 15;
    return *(const u16x4*)((const char*)(t + (size_t)r * 256) + ((chunk ^ (r & 7)) * 16) + off);
}

__global__ __launch_bounds__(256, 3) void sage_fused(const float* __restrict__ h0,
                                                     const float* __restrict__ h1,
                                                     const float* __restrict__ h2,
                                                     const u16* __restrict__ W1t,
                                                     const u16* __restrict__ W2t,
                                                     float* __restrict__ out) {
    // 48 KB total. lA = [48][512]. After layer-1 K-loop + barrier, lA is dead:
    // overlay lNH[48][256] at [0,24K) and lA2[16][512] at [24K,40K).
    __shared__ __align__(16) u16 buf[48 * 512];
    u16* lA  = buf;
    u16* lNH = buf;              // bytes [0, 24576)
    u16* lA2 = buf + 12288;      // bytes [24576, 40960)

    const int b = blockIdx.x;
    const int tid = threadIdx.x;
    const int lane = tid & 63;
    const int wave = tid >> 6;
    const int an = lane & 15;
    const int ak = (lane >> 4) * 8;

    // ---- phase 0: build lA[48][512]  (48 rows x 64 chunks = 3072; 12/thread)
    #pragma unroll
    for (int p = 0; p < 12; ++p) {
        int chunk = p * 256 + tid;
        int r = chunk >> 6;                   // wave-uniform (64 tids per r step)
        int c4 = (chunk & 63) * 4;
        u16x4 sb = {0, 0, 0, 0}, mb = {0, 0, 0, 0};
        if (r < 44) {
            f32x4 sv;
            f32x4 acc = {0.f, 0.f, 0.f, 0.f};
            if (r < 40) {
                // h2 stream: 1.024 GB, never reused -> NON-TEMPORAL (bypass L2/L3)
                const float* sp = h1 + (size_t)(40 * b + r) * 256;
                const float* np = h2 + (size_t)(400 * b + 10 * r) * 256;
                sv = *(const f32x4*)(sp + c4);
                #pragma unroll
                for (int j = 0; j < 10; ++j)
                    acc += __builtin_nontemporal_load((const f32x4*)(np + (size_t)j * 256 + c4));
            } else {
                // h0 self + h1 neighbors (h1 rows reused within block -> cached)
                int i = r - 40;
                const float* sp = h0 + (size_t)(4 * b + i) * 256;
                const float* np = h1 + (size_t)(40 * b + 10 * i) * 256;
                sv = *(const f32x4*)(sp + c4);
                #pragma unroll
                for (int j = 0; j < 10; ++j)
                    acc += *(const f32x4*)(np + (size_t)j * 256 + c4);
            }
            #pragma unroll
            for (int i = 0; i < 4; ++i) { sb[i] = f2bf(sv[i]); mb[i] = f2bf(acc[i] * 0.1f); }
        }
        storeA(lA, r, c4, sb);
        storeA(lA, r, 256 + c4, mb);
    }
    __syncthreads();

    // ---- layer 1: lA[48][512] @ W1t^T -> (sync) -> relu -> bf16 lNH[48][256]
    {
        f32x4 acc[3][4] = {};
        const u16* bp[4];
        #pragma unroll
        for (int nn = 0; nn < 4; ++nn)
            bp[nn] = W1t + (size_t)(wave * 64 + nn * 16 + an) * 512 + ak;
        for (int kt = 0; kt < 8; ++kt) {
            const int kbase = kt * 64;
            s16x8 bF[2][4];
            #pragma unroll
            for (int ks = 0; ks < 2; ++ks)
                #pragma unroll
                for (int nn = 0; nn < 4; ++nn)
                    bF[ks][nn] = *(const s16x8*)(bp[nn] + kbase + ks * 32);
            #pragma unroll
            for (int ks = 0; ks < 2; ++ks) {
                s16x8 aF[3];
                #pragma unroll
                for (int m = 0; m < 3; ++m)
                    aF[m] = readA8(lA, m * 16 + an, kbase + ks * 32 + ak);
                #pragma unroll
                for (int m = 0; m < 3; ++m)
                    #pragma unroll
                    for (int nn = 0; nn < 4; ++nn)
                        acc[m][nn] = __builtin_amdgcn_mfma_f32_16x16x32_bf16(aF[m], bF[ks][nn], acc[m][nn], 0, 0, 0);
            }
        }
        __syncthreads();   // all waves done READING lA -> overlay region reusable
        // C/D layout: col=lane&15, row=(lane>>4)*4+j  [m89-verified]
        const int r0 = (lane >> 4) * 4;
        const int c0 = wave * 64 + an;
        #pragma unroll
        for (int m = 0; m < 3; ++m)
            #pragma unroll
            for (int nn = 0; nn < 4; ++nn)
                #pragma unroll
                for (int j = 0; j < 4; ++j)
                    storeNH1(lNH, m * 16 + r0 + j, c0 + nn * 16, f2bf(fmaxf(acc[m][nn][j], 0.f)));
    }
    __syncthreads();   // lNH complete

    // ---- phase 2: lA2[16][512] := [ nh0 | mean10(nh1) ], rows 4..15 zero
    #pragma unroll
    for (int p = 0; p < 4; ++p) {
        int chunk = p * 256 + tid;
        int r = chunk >> 6;                 // 0..15
        int c4 = (chunk & 63) * 4;
        u16x4 sb = {0, 0, 0, 0}, mb = {0, 0, 0, 0};
        if (r < 4) {
            sb = readNH4(lNH, 40 + r, c4);
            float a[4] = {0.f, 0.f, 0.f, 0.f};
            #pragma unroll
            for (int j = 0; j < 10; ++j) {
                u16x4 v = readNH4(lNH, 10 * r + j, c4);
                #pragma unroll
                for (int i = 0; i < 4; ++i) a[i] += bf2f(v[i]);
            }
            #pragma unroll
            for (int i = 0; i < 4; ++i) mb[i] = f2bf(a[i] * 0.1f);
        }
        storeA(lA2, r, c4, sb);
        storeA(lA2, r, 256 + c4, mb);
    }
    __syncthreads();

    // ---- layer 2: lA2[16][512] @ W2t^T -> f32 out rows 4b..4b+3
    {
        f32x4 acc[4] = {};
        const u16* bp[4];
        #pragma unroll
        for (int nn = 0; nn < 4; ++nn)
            bp[nn] = W2t + (size_t)(wave * 64 + nn * 16 + an) * 512 + ak;
        for (int kt = 0; kt < 8; ++kt) {
            const int kbase = kt * 64;
            s16x8 bF[2][4];
            #pragma unroll
            for (int ks = 0; ks < 2; ++ks)
                #pragma unroll
                for (int nn = 0; nn < 4; ++nn)
                    bF[ks][nn] = *(const s16x8*)(bp[nn] + kbase + ks * 32);
            #pragma unroll
            for (int ks = 0; ks < 2; ++ks) {
                s16x8 aF = readA8(lA2, an, kbase + ks * 32 + ak);
                #pragma unroll
                for (int nn = 0; nn < 4; ++nn)
                    acc[nn] = __builtin_amdgcn_mfma_f32_16x16x32_bf16(aF, bF[ks][nn], acc[nn], 0, 0, 0);
            }
        }
        const int r0 = (lane >> 4) * 4;
        const int c0 = wave * 64 + an;
        #pragma unroll
        for (int nn = 0; nn < 4; ++nn)
            #pragma unroll
            for (int j = 0; j < 4; ++j) {
                int r = r0 + j;
                if (r < 4)
                    out[(size_t)(4 * b + r) * 256 + c0 + nn * 16] = acc[nn][j];
            }
    }
}

extern "C" void kernel_launch(void* const* d_in, const int* in_sizes, int n_in,
                              void* d_out, int out_size, void* d_ws, size_t ws_size,
                              hipStream_t stream) {
    const float* h0  = (const float*)d_in[0];
    const float* h1  = (const float*)d_in[1];
    const float* h2  = (const float*)d_in[2];
    const float* w1s = (const float*)d_in[3];
    const float* w1n = (const float*)d_in[4];
    const float* w2s = (const float*)d_in[5];
    const float* w2n = (const float*)d_in[6];

    char* ws = (char*)d_ws;
    u16* W1t = (u16*)ws; ws += (size_t)256 * 512 * 2;
    u16* W2t = (u16*)ws; ws += (size_t)256 * 512 * 2;
    (void)ws_size; (void)in_sizes; (void)n_in; (void)out_size;

    conv_w2t<<<64, 256, 0, stream>>>(w1s, w1n, w2s, w2n, W1t, W2t);

    // fully fused two-layer SAGE: 2500 blocks x 4 output rows, exact cones
    sage_fused<<<2500, 256, 0, stream>>>(h0, h1, h2, W1t, W2t, (float*)d_out);
}